// Round 5
// baseline (228.326 us; speedup 1.0000x reference)
//
#include <hip/hip_runtime.h>
#include <hip/hip_fp16.h>

#define KE 14.399645351950548f

// ---------------------------------------------------------------------------
// Pack kernel: one 32B row per ML atom (fits entirely inside one 64B line):
//   word0   : f32 KE*q
//   word1-3 : f32 KE*mu_xyz
//   word4   : f16x2 { 3KE*(Qxx - tr/3), 3KE*(Qyy - tr/3) }
//   word5   : f16x2 { 3KE*(Qzz - tr/3), 3KE*(Qxy+Qyx)    }
//   word6   : f16x2 { 3KE*(Qxz+Qzx),    3KE*(Qyz+Qzy)    }
//   word7   : pad
// ---------------------------------------------------------------------------
__global__ __launch_bounds__(256) void pack_ml32_kernel(
    const float* __restrict__ q_ml,
    const float* __restrict__ mu,
    const float* __restrict__ quad,
    float* __restrict__ packed,     // [n_ml * 8] floats (32B rows)
    int n_ml)
{
    int i = blockIdx.x * blockDim.x + threadIdx.x;
    if (i >= n_ml) return;
    const float* Q = quad + 9 * i;
    const float tr3 = (Q[0] + Q[4] + Q[8]) * (1.0f / 3.0f);
    const float s = 3.0f * KE;

    union { __half2 h; float f; } w4, w5, w6;
    w4.h = __floats2half2_rn(s * (Q[0] - tr3), s * (Q[4] - tr3));
    w5.h = __floats2half2_rn(s * (Q[8] - tr3), s * (Q[1] + Q[3]));
    w6.h = __floats2half2_rn(s * (Q[2] + Q[6]), s * (Q[5] + Q[7]));

    float4* p = reinterpret_cast<float4*>(packed + 8 * i);
    p[0] = make_float4(KE * q_ml[i], KE * mu[3 * i + 0],
                       KE * mu[3 * i + 1], KE * mu[3 * i + 2]);
    p[1] = make_float4(w4.f, w5.f, w6.f, 0.0f);
}

// ---------------------------------------------------------------------------
// Main kernel: no LDS, 4 edges/thread, flat grid.
// Per edge: 2 gather dwordx4 (SAME 64B line) + 1 q_mm dword gather.
// ---------------------------------------------------------------------------
__global__ __launch_bounds__(256) void mlmm_elec32_kernel(
    const float* __restrict__ dist,      // [E]
    const float* __restrict__ vec,       // [E,3]
    const float* __restrict__ packed,    // [N_ML*8] packed rows
    const float* __restrict__ q_mm,      // [N_MM]
    const int*   __restrict__ idx_u,     // [E]
    const int*   __restrict__ idx_v,     // [E]
    float* __restrict__ out,             // [E]
    int n4)
{
    int t = blockIdx.x * blockDim.x + threadIdx.x;
    if (t >= n4) return;

    const float4 r4 = reinterpret_cast<const float4*>(dist)[t];
    const int4   u4 = reinterpret_cast<const int4*>(idx_u)[t];
    const int4   w4 = reinterpret_cast<const int4*>(idx_v)[t];
    const float4 va = reinterpret_cast<const float4*>(vec)[3 * t + 0];
    const float4 vb = reinterpret_cast<const float4*>(vec)[3 * t + 1];
    const float4 vc = reinterpret_cast<const float4*>(vec)[3 * t + 2];

    const float rr[4] = {r4.x, r4.y, r4.z, r4.w};
    const float vx[4] = {va.x, va.w, vb.z, vc.y};
    const float vy[4] = {va.y, vb.x, vb.w, vc.z};
    const float vz[4] = {va.z, vb.y, vc.x, vc.w};
    const int   uu[4] = {u4.x, u4.y, u4.z, u4.w};
    const int   ww[4] = {w4.x, w4.y, w4.z, w4.w};

    float res[4];
#pragma unroll
    for (int k = 0; k < 4; ++k) {
        const float r   = rr[k];
        const float B0  = 1.0f / r;
        const float i2  = B0 * B0;
        const float B1  = B0 * i2;           // 1/r^3
        const float B2p = B1 * i2;           // 1/r^5 (3x baked into table)

        const float4* p = reinterpret_cast<const float4*>(packed + 8 * uu[k]);
        const float4 pa = p[0];              // KE*q, KE*mu
        const float4 pb = p[1];              // 6 f16 quad coeffs
        const float qv = q_mm[ww[k]];

        float b0 = pb.x, b1 = pb.y, b2 = pb.z;
        const float2 f0 = __half22float2(*reinterpret_cast<const __half2*>(&b0));
        const float2 f1 = __half22float2(*reinterpret_cast<const __half2*>(&b1));
        const float2 f2 = __half22float2(*reinterpret_cast<const __half2*>(&b2));

        const float x = vx[k], y = vy[k], z = vz[k];
        const float g1 = pa.y * x + pa.z * y + pa.w * z;
        const float g2 = f0.x * (x * x) + f0.y * (y * y) + f1.x * (z * z)
                       + f1.y * (x * y) + f2.x * (x * z) + f2.y * (y * z);

        res[k] = qv * (B0 * pa.x + B1 * g1 - B2p * g2);
    }

    reinterpret_cast<float4*>(out)[t] =
        make_float4(res[0], res[1], res[2], res[3]);
}

// ---------------------------------------------------------------------------
// Fallback (no workspace): direct unpacked kernel.
// ---------------------------------------------------------------------------
__global__ __launch_bounds__(256) void mlmm_elec_fallback_kernel(
    const float* __restrict__ dist, const float* __restrict__ vec,
    const float* __restrict__ q_ml, const float* __restrict__ q_mm,
    const float* __restrict__ mu, const float* __restrict__ quad,
    const int* __restrict__ idx_u, const int* __restrict__ idx_v,
    float* __restrict__ out, int n)
{
    int e = blockIdx.x * blockDim.x + threadIdx.x;
    if (e >= n) return;
    const float r = dist[e], r2 = r * r;
    const float B0 = 1.0f / r, B1 = B0 / r2, B2 = 3.0f * B1 / r2;
    const int u = idx_u[e];
    const float qu = q_ml[u], qv = q_mm[idx_v[e]];
    const float x = vec[3 * e], y = vec[3 * e + 1], z = vec[3 * e + 2];
    const float* m = mu + 3 * u;
    const float g1 = m[0] * x + m[1] * y + m[2] * z;
    const float* Q = quad + 9 * u;
    const float dm = (x * x + y * y + z * z) * (1.0f / 3.0f);
    const float g2 = Q[0] * (x * x - dm) + Q[4] * (y * y - dm) +
                     Q[8] * (z * z - dm) + (Q[1] + Q[3]) * (x * y) +
                     (Q[2] + Q[6]) * (x * z) + (Q[5] + Q[7]) * (y * z);
    out[e] = KE * (B0 * qu * qv + B1 * g1 * qv - B2 * g2 * qv);
}

extern "C" void kernel_launch(void* const* d_in, const int* in_sizes, int n_in,
                              void* d_out, int out_size, void* d_ws, size_t ws_size,
                              hipStream_t stream) {
    const float* dist  = (const float*)d_in[0];
    const float* vec   = (const float*)d_in[1];
    const float* q_ml  = (const float*)d_in[2];
    const float* q_mm  = (const float*)d_in[3];
    const float* mu    = (const float*)d_in[4];
    const float* quad  = (const float*)d_in[5];
    const int*   idx_u = (const int*)d_in[6];
    const int*   idx_v = (const int*)d_in[7];
    float* out = (float*)d_out;

    const int E    = in_sizes[0];
    const int n_ml = in_sizes[2];
    const int n4   = E / 4;                 // E = 2^24, divisible by 4

    const size_t packed_bytes = (size_t)n_ml * 32;

    if (ws_size >= packed_bytes && (E & 3) == 0) {
        float* packed = (float*)d_ws;
        pack_ml32_kernel<<<(n_ml + 255) / 256, 256, 0, stream>>>(
            q_ml, mu, quad, packed, n_ml);
        const int block = 256;
        const int grid  = (n4 + block - 1) / block;
        mlmm_elec32_kernel<<<grid, block, 0, stream>>>(
            dist, vec, packed, q_mm, idx_u, idx_v, out, n4);
    } else {
        mlmm_elec_fallback_kernel<<<(E + 255) / 256, 256, 0, stream>>>(
            dist, vec, q_ml, q_mm, mu, quad, idx_u, idx_v, out, E);
    }
}